// Round 4
// baseline (237.633 us; speedup 1.0000x reference)
//
#include <hip/hip_runtime.h>
#include <math.h>

// YOLOX loss, fixed shapes: B=32, A = 80*80 + 40*40 + 20*20 = 8400, 85 channels.
constexpr int A_TOTAL = 8400;

__device__ __forceinline__ float bce(float x, float t) {
    // max(x,0) - x*t + softplus(-|x|); hw exp/log (v_exp_f32/v_log_f32)
    float ax = fabsf(x);
    float sp = __logf(1.0f + __expf(-ax));
    return fmaxf(x, 0.0f) - x * t + sp;
}

__device__ __forceinline__ void block_reduce_atomic(float v, float w, double* acc,
                                                    bool two) {
    for (int off = 32; off > 0; off >>= 1) {
        v += __shfl_down(v, off, 64);
        if (two) w += __shfl_down(w, off, 64);
    }
    __shared__ float s_v[4], s_w[4];
    int wid  = threadIdx.x >> 6;
    int lane = threadIdx.x & 63;
    if (lane == 0) { s_v[wid] = v; s_w[wid] = w; }
    __syncthreads();
    if (threadIdx.x == 0) {
        float bv = s_v[0] + s_v[1] + s_v[2] + s_v[3];
        atomicAdd(&acc[0], (double)bv);
        if (two) {
            float bw = s_w[0] + s_w[1] + s_w[2] + s_w[3];
            atomicAdd(&acc[1], (double)bw);
        }
    }
}

// Kernel 1: IoU + objectness + fg count. One thread per anchor. Fully coalesced.
__global__ __launch_bounds__(256) void yolox_iou_obj(
    const float* __restrict__ out0, const float* __restrict__ out1,
    const float* __restrict__ out2, const float* __restrict__ regt,
    const int* __restrict__ fgm, double* __restrict__ acc, int B)
{
    int g = blockIdx.x * blockDim.x + threadIdx.x;
    float local = 0.0f, fgl = 0.0f;
    int total = B * A_TOTAL;
    if (g < total) {
        int b = g / A_TOTAL;
        int r = g - b * A_TOTAL;
        const float* obase; int HW; float stride; int a, gx, gy;
        if (r < 6400) {
            obase = out0 + (size_t)b * 85 * 6400; HW = 6400; stride = 8.0f;
            a = r;        gx = a % 80; gy = a / 80;
        } else if (r < 8000) {
            obase = out1 + (size_t)b * 85 * 1600; HW = 1600; stride = 16.0f;
            a = r - 6400; gx = a % 40; gy = a / 40;
        } else {
            obase = out2 + (size_t)b * 85 * 400;  HW = 400;  stride = 32.0f;
            a = r - 8000; gx = a % 20; gy = a / 20;
        }
        float tx   = obase[a];
        float ty   = obase[(size_t)1 * HW + a];
        float tw   = obase[(size_t)2 * HW + a];
        float th   = obase[(size_t)3 * HW + a];
        float tobj = obase[(size_t)4 * HW + a];

        float px = (tx + (float)gx) * stride;
        float py = (ty + (float)gy) * stride;
        float pw = __expf(tw) * stride;
        float ph = __expf(th) * stride;

        float4 t = reinterpret_cast<const float4*>(regt)[g];
        float fgv = (float)fgm[g];

        float tlx = fmaxf(px - pw * 0.5f, t.x - t.z * 0.5f);
        float tly = fmaxf(py - ph * 0.5f, t.y - t.w * 0.5f);
        float brx = fminf(px + pw * 0.5f, t.x + t.z * 0.5f);
        float bry = fminf(py + ph * 0.5f, t.y + t.w * 0.5f);
        float area_p = pw * ph;
        float area_g = t.z * t.w;
        float en = ((tlx < brx) && (tly < bry)) ? 1.0f : 0.0f;
        float area_i = (brx - tlx) * (bry - tly) * en;
        float area_u = area_p + area_g - area_i;
        float iou = area_i / (area_u + 1e-16f);
        float l_iou = 1.0f - iou * iou;

        local = 5.0f * l_iou * fgv + bce(tobj, fgv);
        fgl = fgv;
    }
    block_reduce_atomic(local, fgl, acc, true);
}

// Kernel 2: classification BCE. 4 threads per anchor, each owns 20 classes.
// DENSE: loads are unconditional; fg mask applied arithmetically. fg-skipping
// loads (round 3) degraded HBM to 1.15 TB/s by turning streams into scattered
// 64B/320B holes; dense streams should run at 4.5-6 TB/s.
__global__ __launch_bounds__(256) void yolox_cls(
    const float* __restrict__ out0, const float* __restrict__ out1,
    const float* __restrict__ out2, const float* __restrict__ clst,
    const int* __restrict__ fgm, double* __restrict__ acc, int B)
{
    int t = blockIdx.x * blockDim.x + threadIdx.x;
    float local = 0.0f;
    int total4 = B * A_TOTAL * 4;
    if (t < total4) {
        int g = t >> 2;          // anchor
        int q = t & 3;           // class-quarter (20 classes)
        float fgv = (float)fgm[g];
        int b = g / A_TOTAL;
        int r = g - b * A_TOTAL;
        const float* cp; int HW; int a;
        if (r < 6400) {
            cp = out0 + (size_t)b * 85 * 6400 + (size_t)5 * 6400; HW = 6400; a = r;
        } else if (r < 8000) {
            cp = out1 + (size_t)b * 85 * 1600 + (size_t)5 * 1600; HW = 1600; a = r - 6400;
        } else {
            cp = out2 + (size_t)b * 85 * 400  + (size_t)5 * 400;  HW = 400;  a = r - 8000;
        }
        cp += a + (size_t)(q * 20) * HW;
        const float4* ct = reinterpret_cast<const float4*>(clst + (size_t)g * 80 + q * 20);
        float cl = 0.0f;
        #pragma unroll
        for (int i = 0; i < 5; ++i) {
            float4 tv = ct[i];
            float x0 = cp[(size_t)(4 * i + 0) * HW];
            float x1 = cp[(size_t)(4 * i + 1) * HW];
            float x2 = cp[(size_t)(4 * i + 2) * HW];
            float x3 = cp[(size_t)(4 * i + 3) * HW];
            cl += bce(x0, tv.x) + bce(x1, tv.y) + bce(x2, tv.z) + bce(x3, tv.w);
        }
        local = cl * fgv;
    }
    block_reduce_atomic(local, 0.0f, acc, false);
}

__global__ void yolox_final(const double* __restrict__ acc, float* __restrict__ out) {
    out[0] = (float)(acc[0] / fmax(acc[1], 1.0));
}

extern "C" void kernel_launch(void* const* d_in, const int* in_sizes, int n_in,
                              void* d_out, int out_size, void* d_ws, size_t ws_size,
                              hipStream_t stream) {
    const float* out0 = (const float*)d_in[0];
    const float* out1 = (const float*)d_in[1];
    const float* out2 = (const float*)d_in[2];
    const float* regt = (const float*)d_in[3];
    const float* clst = (const float*)d_in[4];
    const int*   fgm  = (const int*)d_in[5];

    int B = in_sizes[0] / (85 * 6400);
    double* acc = (double*)d_ws;
    hipMemsetAsync(acc, 0, 2 * sizeof(double), stream);

    int total  = B * A_TOTAL;
    int blocks1 = (total + 255) / 256;
    int blocks2 = (total * 4 + 255) / 256;
    hipLaunchKernelGGL(yolox_iou_obj, dim3(blocks1), dim3(256), 0, stream,
                       out0, out1, out2, regt, fgm, acc, B);
    hipLaunchKernelGGL(yolox_cls, dim3(blocks2), dim3(256), 0, stream,
                       out0, out1, out2, clst, fgm, acc, B);
    hipLaunchKernelGGL(yolox_final, dim3(1), dim3(1), 0, stream, acc, (float*)d_out);
}

// Round 5
// 208.023 us; speedup vs baseline: 1.1423x; 1.1423x over previous
//
#include <hip/hip_runtime.h>
#include <math.h>

// YOLOX loss, fixed shapes: B=32, A = 80*80 + 40*40 + 20*20 = 8400, 85 channels.
constexpr int A_TOTAL = 8400;
constexpr int AGPI    = A_TOTAL / 4;   // anchor-groups per image = 2100

__device__ __forceinline__ float bce(float x, float t) {
    // max(x,0) - x*t + softplus(-|x|); hw exp/log (v_exp_f32/v_log_f32)
    float ax = fabsf(x);
    float sp = __logf(1.0f + __expf(-ax));
    return fmaxf(x, 0.0f) - x * t + sp;
}

__device__ __forceinline__ float get4(const float4& v, int j) {
    // j is a compile-time constant after unrolling -> folds to a register pick
    return j == 0 ? v.x : (j == 1 ? v.y : (j == 2 ? v.z : v.w));
}

// Fused kernel. Thread layout: t = ag*4 + q.
//   ag = global anchor group (4 consecutive anchors), q = class quarter.
// Each thread: cls BCE for 4 anchors x 20 classes (fat, float4 loads both sides)
//              + IoU/obj for anchor a0+q (balanced across q).
__global__ __launch_bounds__(256) void yolox_fused(
    const float* __restrict__ out0, const float* __restrict__ out1,
    const float* __restrict__ out2, const float* __restrict__ regt,
    const float* __restrict__ clst, const int* __restrict__ fgm,
    double* __restrict__ acc, int B)
{
    int t  = blockIdx.x * blockDim.x + threadIdx.x;
    int q  = t & 3;
    int ag = t >> 2;
    int b  = ag / AGPI;
    int rg = ag - b * AGPI;
    int a0 = rg * 4;                       // anchor index within image (mult of 4)

    const float* obase; int HW; float stride; int al; int W;
    if (a0 < 6400)      { obase = out0 + (size_t)b * 85 * 6400; HW = 6400; stride = 8.0f;  al = a0;        W = 80; }
    else if (a0 < 8000) { obase = out1 + (size_t)b * 85 * 1600; HW = 1600; stride = 16.0f; al = a0 - 6400; W = 40; }
    else                { obase = out2 + (size_t)b * 85 * 400;  HW = 400;  stride = 32.0f; al = a0 - 8000; W = 20; }

    // ---- cls logits: 20 x float4 across 4 consecutive anchors (16B/lane) ----
    float4 L[20];
    const float* cb = obase + (size_t)(5 + q * 20) * HW + al;
    #pragma unroll
    for (int i = 0; i < 20; ++i)
        L[i] = *reinterpret_cast<const float4*>(cb + (size_t)i * HW);

    // fg for the 4 anchors (one int4)
    int4 fg4 = *reinterpret_cast<const int4*>(fgm + (size_t)b * A_TOTAL + a0);
    float fgf[4] = { (float)fg4.x, (float)fg4.y, (float)fg4.z, (float)fg4.w };

    // ---- cls BCE: per anchor j, 20 classes ----
    float local = 0.0f;
    #pragma unroll
    for (int j = 0; j < 4; ++j) {
        const float4* tp = reinterpret_cast<const float4*>(
            clst + ((size_t)b * A_TOTAL + a0 + j) * 80 + q * 20);
        float tg[20];
        #pragma unroll
        for (int i5 = 0; i5 < 5; ++i5) {
            float4 tv = tp[i5];
            tg[4 * i5 + 0] = tv.x; tg[4 * i5 + 1] = tv.y;
            tg[4 * i5 + 2] = tv.z; tg[4 * i5 + 3] = tv.w;
        }
        float s = 0.0f;
        #pragma unroll
        for (int i = 0; i < 20; ++i)
            s += bce(get4(L[i], j), tg[i]);
        local += s * fgf[j];
    }

    // ---- IoU + objectness for anchor a0+q ----
    {
        int aa  = al + q;                   // local anchor
        int a   = a0 + q;                   // image anchor (for grid coords)
        int gx  = a % W == a % W ? (aa % W) : 0;  // aa and a differ by level offset; use aa
        gx = aa % W;
        int gy  = aa / W;
        float tx   = obase[aa];
        float ty   = obase[(size_t)1 * HW + aa];
        float tw   = obase[(size_t)2 * HW + aa];
        float th   = obase[(size_t)3 * HW + aa];
        float tobj = obase[(size_t)4 * HW + aa];

        float px = (tx + (float)gx) * stride;
        float py = (ty + (float)gy) * stride;
        float pw = __expf(tw) * stride;
        float ph = __expf(th) * stride;

        float4 rt = reinterpret_cast<const float4*>(regt)[(size_t)b * A_TOTAL + a];
        float fgv = get4(make_float4(fgf[0], fgf[1], fgf[2], fgf[3]), q);

        float tlx = fmaxf(px - pw * 0.5f, rt.x - rt.z * 0.5f);
        float tly = fmaxf(py - ph * 0.5f, rt.y - rt.w * 0.5f);
        float brx = fminf(px + pw * 0.5f, rt.x + rt.z * 0.5f);
        float bry = fminf(py + ph * 0.5f, rt.y + rt.w * 0.5f);
        float area_p = pw * ph;
        float area_g = rt.z * rt.w;
        float en = ((tlx < brx) && (tly < bry)) ? 1.0f : 0.0f;
        float area_i = (brx - tlx) * (bry - tly) * en;
        float area_u = area_p + area_g - area_i;
        float iou = area_i / (area_u + 1e-16f);
        float l_iou = 1.0f - iou * iou;

        local += 5.0f * l_iou * fgv + bce(tobj, fgv);

        // fg count: each anchor counted exactly once (by its q-thread)
        float fgl = fgv;

        // ---- block reduction + atomics ----
        for (int off = 32; off > 0; off >>= 1) {
            local += __shfl_down(local, off, 64);
            fgl   += __shfl_down(fgl,   off, 64);
        }
        __shared__ float s_v[4], s_w[4];
        int wid  = threadIdx.x >> 6;
        int lane = threadIdx.x & 63;
        if (lane == 0) { s_v[wid] = local; s_w[wid] = fgl; }
        __syncthreads();
        if (threadIdx.x == 0) {
            atomicAdd(&acc[0], (double)(s_v[0] + s_v[1] + s_v[2] + s_v[3]));
            atomicAdd(&acc[1], (double)(s_w[0] + s_w[1] + s_w[2] + s_w[3]));
        }
    }
}

__global__ void yolox_final(const double* __restrict__ acc, float* __restrict__ out) {
    out[0] = (float)(acc[0] / fmax(acc[1], 1.0));
}

extern "C" void kernel_launch(void* const* d_in, const int* in_sizes, int n_in,
                              void* d_out, int out_size, void* d_ws, size_t ws_size,
                              hipStream_t stream) {
    const float* out0 = (const float*)d_in[0];
    const float* out1 = (const float*)d_in[1];
    const float* out2 = (const float*)d_in[2];
    const float* regt = (const float*)d_in[3];
    const float* clst = (const float*)d_in[4];
    const int*   fgm  = (const int*)d_in[5];

    int B = in_sizes[0] / (85 * 6400);
    double* acc = (double*)d_ws;
    hipMemsetAsync(acc, 0, 2 * sizeof(double), stream);

    int total  = B * A_TOTAL;                 // one thread per (anchor-group, quarter)
    int blocks = (total + 255) / 256;         // 1050 blocks for B=32
    hipLaunchKernelGGL(yolox_fused, dim3(blocks), dim3(256), 0, stream,
                       out0, out1, out2, regt, clst, fgm, acc, B);
    hipLaunchKernelGGL(yolox_final, dim3(1), dim3(1), 0, stream, acc, (float*)d_out);
}